// Round 3
// baseline (1220.406 us; speedup 1.0000x reference)
//
#include <hip/hip_runtime.h>

// Problem constants (IndyLSTM: B=32, T=2048, I=H=512)
#define B_  32
#define T_  2048
#define H_  512
#define K_  512          // input size I (GEMM K)
#define N_  2048         // 4*H (GEMM N), column index n' = h*4 + g  (g: 0=f,1=i,2=o,3=c)

typedef __attribute__((ext_vector_type(8))) __bf16 bf16x8;
typedef __attribute__((ext_vector_type(4))) __bf16 bf16x4;
typedef __attribute__((ext_vector_type(4))) float  floatx4;

// ---------------- conversion kernels (split bf16: v = hi + lo, fp32-accurate) ----------------

__global__ void convert_x(const float* __restrict__ x,
                          __bf16* __restrict__ xh, __bf16* __restrict__ xl, int n4) {
    int i = blockIdx.x * blockDim.x + threadIdx.x;
    if (i < n4) {
        const float4 v = ((const float4*)x)[i];
        bf16x4 hi, lo;
        hi[0] = (__bf16)v.x; lo[0] = (__bf16)(v.x - (float)hi[0]);
        hi[1] = (__bf16)v.y; lo[1] = (__bf16)(v.y - (float)hi[1]);
        hi[2] = (__bf16)v.z; lo[2] = (__bf16)(v.z - (float)hi[2]);
        hi[3] = (__bf16)v.w; lo[3] = (__bf16)(v.w - (float)hi[3]);
        *(bf16x4*)(xh + 4 * (size_t)i) = hi;
        *(bf16x4*)(xl + 4 * (size_t)i) = lo;
    }
}

// Wt[n'][k] = W_g[k][h] with n' = h*4+g  (k-contiguous => "B^T" layout for GEMM)
__global__ void convert_w(const float* __restrict__ Wf, const float* __restrict__ Wi,
                          const float* __restrict__ Wo, const float* __restrict__ Wc,
                          __bf16* __restrict__ Wh, __bf16* __restrict__ Wl) {
    int o = blockIdx.x * blockDim.x + threadIdx.x;   // [0, N_*K_)
    int k = o & (K_ - 1);
    int n = o >> 9;          // n' in [0,2048)
    int g = n & 3, h = n >> 2;
    const float* W = (g == 0) ? Wf : (g == 1) ? Wi : (g == 2) ? Wo : Wc;
    float v = W[k * H_ + h];
    __bf16 hi = (__bf16)v;
    Wh[o] = hi;
    Wl[o] = (__bf16)(v - (float)hi);
}

// ---------------- split-bf16 MFMA GEMM ----------------
// C[m][n] = sum_k A[m][k]*Bt[n][k] with A ~ Ah+Al, Bt ~ Bh+Bl
// acc += Ah*Bh + Ah*Bl + Al*Bh   (fp32-accurate to ~2^-18 relative)
#define BM 128
#define BN 128
#define BK 32

__device__ __forceinline__ void async_copy16(const __bf16* g, __bf16* l) {
    __builtin_amdgcn_global_load_lds(
        (const __attribute__((address_space(1))) void*)g,
        (__attribute__((address_space(3))) void*)l,
        16, 0, 0);
}

__global__ __launch_bounds__(256, 2)
void gemm_bt(const __bf16* __restrict__ Ah, const __bf16* __restrict__ Al,
             const __bf16* __restrict__ Bh, const __bf16* __restrict__ Bl,
             float* __restrict__ C) {
    __shared__ __align__(16) __bf16 AsH[BM * BK];
    __shared__ __align__(16) __bf16 AsL[BM * BK];
    __shared__ __align__(16) __bf16 BsH[BN * BK];
    __shared__ __align__(16) __bf16 BsL[BN * BK];

    const int tid  = threadIdx.x;
    const int lane = tid & 63;
    const int wave = tid >> 6;

    const int ntiles = N_ / BN;                 // 16
    const int bm = blockIdx.x / ntiles;
    const int bn = blockIdx.x % ntiles;
    const int m0 = bm * BM, n0 = bn * BN;

    const int waveM = (wave & 1) * 64;
    const int waveN = (wave >> 1) * 64;
    const int lm = lane & 15;
    const int lk = (lane >> 4) * 8;

    floatx4 acc[4][4] = {};

    // staging: each tile is 512 x 16B chunks; thread handles chunks tid and tid+256
    const int c0 = tid, c1 = tid + 256;
    const size_t a_g0 = (size_t)(m0 + (c0 >> 2)) * K_ + (c0 & 3) * 8;
    const size_t a_g1 = (size_t)(m0 + (c1 >> 2)) * K_ + (c1 & 3) * 8;
    const size_t b_g0 = (size_t)(n0 + (c0 >> 2)) * K_ + (c0 & 3) * 8;
    const size_t b_g1 = (size_t)(n0 + (c1 >> 2)) * K_ + (c1 & 3) * 8;
    const int w512 = wave * 512;                // wave-uniform LDS base (1024B per wave)

    for (int k0 = 0; k0 < K_; k0 += BK) {
        async_copy16(Ah + a_g0 + k0, AsH + w512);
        async_copy16(Ah + a_g1 + k0, AsH + 2048 + w512);
        async_copy16(Al + a_g0 + k0, AsL + w512);
        async_copy16(Al + a_g1 + k0, AsL + 2048 + w512);
        async_copy16(Bh + b_g0 + k0, BsH + w512);
        async_copy16(Bh + b_g1 + k0, BsH + 2048 + w512);
        async_copy16(Bl + b_g0 + k0, BsL + w512);
        async_copy16(Bl + b_g1 + k0, BsL + 2048 + w512);
        __syncthreads();

        bf16x8 ah[4], al[4], bh[4], bl[4];
#pragma unroll
        for (int mi = 0; mi < 4; mi++) {
            ah[mi] = *(const bf16x8*)(AsH + (waveM + mi * 16 + lm) * BK + lk);
            al[mi] = *(const bf16x8*)(AsL + (waveM + mi * 16 + lm) * BK + lk);
        }
#pragma unroll
        for (int ni = 0; ni < 4; ni++) {
            bh[ni] = *(const bf16x8*)(BsH + (waveN + ni * 16 + lm) * BK + lk);
            bl[ni] = *(const bf16x8*)(BsL + (waveN + ni * 16 + lm) * BK + lk);
        }
#pragma unroll
        for (int mi = 0; mi < 4; mi++)
#pragma unroll
            for (int ni = 0; ni < 4; ni++) {
                acc[mi][ni] = __builtin_amdgcn_mfma_f32_16x16x32_bf16(
                    ah[mi], bh[ni], acc[mi][ni], 0, 0, 0);
                acc[mi][ni] = __builtin_amdgcn_mfma_f32_16x16x32_bf16(
                    ah[mi], bl[ni], acc[mi][ni], 0, 0, 0);
                acc[mi][ni] = __builtin_amdgcn_mfma_f32_16x16x32_bf16(
                    al[mi], bh[ni], acc[mi][ni], 0, 0, 0);
            }
        __syncthreads();
    }

    // epilogue: C/D layout col = lane&15, row = (lane>>4)*4 + r
#pragma unroll
    for (int mi = 0; mi < 4; mi++) {
        const int m = m0 + waveM + mi * 16 + (lane >> 4) * 4;
#pragma unroll
        for (int ni = 0; ni < 4; ni++) {
            const int n = n0 + waveN + ni * 16 + lm;
#pragma unroll
            for (int r = 0; r < 4; r++)
                C[(size_t)(m + r) * N_ + n] = acc[mi][ni][r];
        }
    }
}

// ---------------- recurrent scan ----------------
// Branch-free gates:
//   sigmoid(x) = rcp(1 + e^{-x})           (rcp(inf)=0 handles saturation)
//   tanh(x)    = 1 - 2*rcp(1 + e^{2x})
// Critical path per step kept to: fma -> exp -> add -> rcp -> [fma] -> fma(c)
// -> mul -> exp -> add -> rcp -> fma -> mul.

#define PF 8   // prefetch depth (ring); over-prefetches harmlessly into adjacent ws region

__global__ __launch_bounds__(64)
void scan_kernel(const float* __restrict__ pre,   // [Bc*T][2048] fp32, col = j*4+g
                 const float* __restrict__ uf_, const float* __restrict__ bfv_,
                 const float* __restrict__ ui_, const float* __restrict__ bi_,
                 const float* __restrict__ uo_, const float* __restrict__ bo_,
                 const float* __restrict__ uc_, const float* __restrict__ bc_,
                 float* __restrict__ out, int b0) {
    const int tid = blockIdx.x * 64 + threadIdx.x;
    const int bl = tid >> 9;       // local batch index within chunk
    const int j  = tid & 511;

    // hoisted, pre-negated/scaled so per-step gate arg is a single fma on the h-chain
    const float nuf = -uf_[j], nbf = -bfv_[j];
    const float nui = -ui_[j], nbi = -bi_[j];
    const float nuo = -uo_[j], nbo = -bo_[j];
    const float uc2 = 2.0f * uc_[j], bc2 = 2.0f * bc_[j];

    const float* p = pre + (size_t)bl * T_ * N_ + (size_t)j * 4;
    float* o = out + ((size_t)(b0 + bl) * T_) * H_ + j;

    float h = 0.0f, c = 0.0f;

    floatx4 ring[PF];
#pragma unroll
    for (int i = 0; i < PF; i++)
        ring[i] = *(const floatx4*)(p + (size_t)i * N_);
    const float* pl = p + (size_t)PF * N_;

#pragma unroll 8
    for (int t = 0; t < T_; ++t) {
        floatx4 q = ring[t & (PF - 1)];
        ring[t & (PF - 1)] = *(const floatx4*)pl;   // over-prefetch past end: lands in ws, unused
        pl += (size_t)N_;

        // off-chain combine of loaded gate value with bias (and sign/scale folds)
        float a0 = nbf - q[0];                      // -(q0 + bf)
        float a1 = nbi - q[1];
        float a2 = nbo - q[2];
        float a3 = __builtin_fmaf(q[3], 2.0f, bc2); // 2*(q3 + bc)

        float e0 = __expf(__builtin_fmaf(h, nuf, a0));   // e^{-g0}
        float e1 = __expf(__builtin_fmaf(h, nui, a1));   // e^{-g1}
        float e2 = __expf(__builtin_fmaf(h, nuo, a2));   // e^{-g2}
        float e3 = __expf(__builtin_fmaf(h, uc2, a3));   // e^{+2*g3}

        float f  = __builtin_amdgcn_rcpf(1.0f + e0);
        float ii = __builtin_amdgcn_rcpf(1.0f + e1);
        float ot = __builtin_amdgcn_rcpf(1.0f + e2);
        float z  = __builtin_fmaf(-2.0f, __builtin_amdgcn_rcpf(1.0f + e3), 1.0f);

        c = __builtin_fmaf(f, c, ii * z);

        float ec = __expf(c + c);                        // e^{2c}
        float tc = __builtin_fmaf(-2.0f, __builtin_amdgcn_rcpf(1.0f + ec), 1.0f);
        h = ot * tc;

        o[(size_t)t * H_] = h;
    }
}

// ---------------- launch ----------------

extern "C" void kernel_launch(void* const* d_in, const int* in_sizes, int n_in,
                              void* d_out, int out_size, void* d_ws, size_t ws_size,
                              hipStream_t stream) {
    const float* x  = (const float*)d_in[0];
    const float* Wf = (const float*)d_in[1];
    const float* uf = (const float*)d_in[2];
    const float* bf = (const float*)d_in[3];
    const float* Wi = (const float*)d_in[4];
    const float* ui = (const float*)d_in[5];
    const float* bi = (const float*)d_in[6];
    const float* Wo = (const float*)d_in[7];
    const float* uo = (const float*)d_in[8];
    const float* bo = (const float*)d_in[9];
    const float* Wc = (const float*)d_in[10];
    const float* uc = (const float*)d_in[11];
    const float* bc = (const float*)d_in[12];
    float* out = (float*)d_out;

    const size_t xB = (size_t)B_ * T_ * K_ * 2;   // 64 MiB each (hi, lo)
    const size_t wB = (size_t)N_ * K_ * 2;        //  2 MiB each (hi, lo)

    // choose batch chunk so pre(fp32) + x splits + W splits fit in ws
    int Bc = 32;
    while (Bc > 1 && ws_size < (size_t)Bc * T_ * N_ * 4 + 2 * xB + 2 * wB) Bc >>= 1;
    const size_t preB = (size_t)Bc * T_ * N_ * 4;

    float*  pre = (float*)d_ws;
    __bf16* xh  = (__bf16*)((char*)d_ws + preB);
    __bf16* xl  = (__bf16*)((char*)d_ws + preB + xB);
    __bf16* Wh  = (__bf16*)((char*)d_ws + preB + 2 * xB);
    __bf16* Wl  = (__bf16*)((char*)d_ws + preB + 2 * xB + wB);

    convert_x<<<(B_ * T_ * K_ / 4 + 255) / 256, 256, 0, stream>>>(x, xh, xl, B_ * T_ * K_ / 4);
    convert_w<<<(N_ * K_) / 256, 256, 0, stream>>>(Wf, Wi, Wo, Wc, Wh, Wl);

    // h_t, c_t outputs are zeros
    hipMemsetAsync((char*)d_out + (size_t)B_ * T_ * H_ * 4, 0,
                   2 * (size_t)B_ * H_ * 4, stream);

    for (int b0 = 0; b0 < B_; b0 += Bc) {
        const int Mc = Bc * T_;
        gemm_bt<<<dim3((Mc / BM) * (N_ / BN)), 256, 0, stream>>>(
            xh + (size_t)b0 * T_ * K_, xl + (size_t)b0 * T_ * K_, Wh, Wl, pre);
        scan_kernel<<<dim3(Bc * 8), 64, 0, stream>>>(
            pre, uf, bf, ui, bi, uo, bo, uc, bc, out, b0);
    }
}

// Round 4
// 841.340 us; speedup vs baseline: 1.4506x; 1.4506x over previous
//
#include <hip/hip_runtime.h>
#include <hip/hip_fp16.h>

// Problem constants (IndyLSTM: B=32, T=2048, I=H=512)
#define B_  32
#define T_  2048
#define H_  512
#define K_  512          // input size I (GEMM K)
#define N_  2048         // 4*H (GEMM N), column index n' = h*4 + g  (g: 0=f,1=i,2=o,3=c)

typedef __attribute__((ext_vector_type(8))) __bf16 bf16x8;
typedef __attribute__((ext_vector_type(4))) __bf16 bf16x4;
typedef __attribute__((ext_vector_type(4))) float  floatx4;

// ---------------- conversion kernels (split bf16: v = hi + lo, fp32-accurate) ----------------

__global__ void convert_x(const float* __restrict__ x,
                          __bf16* __restrict__ xh, __bf16* __restrict__ xl, int n4) {
    int i = blockIdx.x * blockDim.x + threadIdx.x;
    if (i < n4) {
        const float4 v = ((const float4*)x)[i];
        bf16x4 hi, lo;
        hi[0] = (__bf16)v.x; lo[0] = (__bf16)(v.x - (float)hi[0]);
        hi[1] = (__bf16)v.y; lo[1] = (__bf16)(v.y - (float)hi[1]);
        hi[2] = (__bf16)v.z; lo[2] = (__bf16)(v.z - (float)hi[2]);
        hi[3] = (__bf16)v.w; lo[3] = (__bf16)(v.w - (float)hi[3]);
        *(bf16x4*)(xh + 4 * (size_t)i) = hi;
        *(bf16x4*)(xl + 4 * (size_t)i) = lo;
    }
}

// Wt[n'][k] = W_g[k][h] with n' = h*4+g  (k-contiguous => "B^T" layout for GEMM)
__global__ void convert_w(const float* __restrict__ Wf, const float* __restrict__ Wi,
                          const float* __restrict__ Wo, const float* __restrict__ Wc,
                          __bf16* __restrict__ Wh, __bf16* __restrict__ Wl) {
    int o = blockIdx.x * blockDim.x + threadIdx.x;   // [0, N_*K_)
    int k = o & (K_ - 1);
    int n = o >> 9;          // n' in [0,2048)
    int g = n & 3, h = n >> 2;
    const float* W = (g == 0) ? Wf : (g == 1) ? Wi : (g == 2) ? Wo : Wc;
    float v = W[k * H_ + h];
    __bf16 hi = (__bf16)v;
    Wh[o] = hi;
    Wl[o] = (__bf16)(v - (float)hi);
}

// ---------------- split-bf16 MFMA GEMM ----------------
// C[m][n] = sum_k A[m][k]*Bt[n][k] with A ~ Ah+Al, Bt ~ Bh+Bl
// acc += Ah*Bh + Ah*Bl + Al*Bh   (fp32-accurate to ~2^-18 relative); C stored fp16
#define BM 128
#define BN 128
#define BK 32

__device__ __forceinline__ void async_copy16(const __bf16* g, __bf16* l) {
    __builtin_amdgcn_global_load_lds(
        (const __attribute__((address_space(1))) void*)g,
        (__attribute__((address_space(3))) void*)l,
        16, 0, 0);
}

__global__ __launch_bounds__(256, 2)
void gemm_bt(const __bf16* __restrict__ Ah, const __bf16* __restrict__ Al,
             const __bf16* __restrict__ Bh, const __bf16* __restrict__ Bl,
             __half* __restrict__ C) {
    __shared__ __align__(16) __bf16 AsH[BM * BK];
    __shared__ __align__(16) __bf16 AsL[BM * BK];
    __shared__ __align__(16) __bf16 BsH[BN * BK];
    __shared__ __align__(16) __bf16 BsL[BN * BK];

    const int tid  = threadIdx.x;
    const int lane = tid & 63;
    const int wave = tid >> 6;

    const int ntiles = N_ / BN;                 // 16
    const int bm = blockIdx.x / ntiles;
    const int bn = blockIdx.x % ntiles;
    const int m0 = bm * BM, n0 = bn * BN;

    const int waveM = (wave & 1) * 64;
    const int waveN = (wave >> 1) * 64;
    const int lm = lane & 15;
    const int lk = (lane >> 4) * 8;

    floatx4 acc[4][4] = {};

    // staging: each tile is 512 x 16B chunks; thread handles chunks tid and tid+256
    const int c0 = tid, c1 = tid + 256;
    const size_t a_g0 = (size_t)(m0 + (c0 >> 2)) * K_ + (c0 & 3) * 8;
    const size_t a_g1 = (size_t)(m0 + (c1 >> 2)) * K_ + (c1 & 3) * 8;
    const size_t b_g0 = (size_t)(n0 + (c0 >> 2)) * K_ + (c0 & 3) * 8;
    const size_t b_g1 = (size_t)(n0 + (c1 >> 2)) * K_ + (c1 & 3) * 8;
    const int w512 = wave * 512;                // wave-uniform LDS base (1024B per wave)

    for (int k0 = 0; k0 < K_; k0 += BK) {
        async_copy16(Ah + a_g0 + k0, AsH + w512);
        async_copy16(Ah + a_g1 + k0, AsH + 2048 + w512);
        async_copy16(Al + a_g0 + k0, AsL + w512);
        async_copy16(Al + a_g1 + k0, AsL + 2048 + w512);
        async_copy16(Bh + b_g0 + k0, BsH + w512);
        async_copy16(Bh + b_g1 + k0, BsH + 2048 + w512);
        async_copy16(Bl + b_g0 + k0, BsL + w512);
        async_copy16(Bl + b_g1 + k0, BsL + 2048 + w512);
        __syncthreads();

        bf16x8 ah[4], al[4], bh[4], bl[4];
#pragma unroll
        for (int mi = 0; mi < 4; mi++) {
            ah[mi] = *(const bf16x8*)(AsH + (waveM + mi * 16 + lm) * BK + lk);
            al[mi] = *(const bf16x8*)(AsL + (waveM + mi * 16 + lm) * BK + lk);
        }
#pragma unroll
        for (int ni = 0; ni < 4; ni++) {
            bh[ni] = *(const bf16x8*)(BsH + (waveN + ni * 16 + lm) * BK + lk);
            bl[ni] = *(const bf16x8*)(BsL + (waveN + ni * 16 + lm) * BK + lk);
        }
#pragma unroll
        for (int mi = 0; mi < 4; mi++)
#pragma unroll
            for (int ni = 0; ni < 4; ni++) {
                acc[mi][ni] = __builtin_amdgcn_mfma_f32_16x16x32_bf16(
                    ah[mi], bh[ni], acc[mi][ni], 0, 0, 0);
                acc[mi][ni] = __builtin_amdgcn_mfma_f32_16x16x32_bf16(
                    ah[mi], bl[ni], acc[mi][ni], 0, 0, 0);
                acc[mi][ni] = __builtin_amdgcn_mfma_f32_16x16x32_bf16(
                    al[mi], bh[ni], acc[mi][ni], 0, 0, 0);
            }
        __syncthreads();
    }

    // epilogue: C/D layout col = lane&15, row = (lane>>4)*4 + r; store fp16
#pragma unroll
    for (int mi = 0; mi < 4; mi++) {
        const int m = m0 + waveM + mi * 16 + (lane >> 4) * 4;
#pragma unroll
        for (int ni = 0; ni < 4; ni++) {
            const int n = n0 + waveN + ni * 16 + lm;
#pragma unroll
            for (int r = 0; r < 4; r++)
                C[(size_t)(m + r) * N_ + n] = __float2half(acc[mi][ni][r]);
        }
    }
}

// ---------------- quad-cooperative recurrent scan ----------------
// 4 lanes per (b,j) chain, one gate per lane (g = lane&3: 0=f,1=i,2=o,3=z).
// Uniform per-lane math with folded constants:
//   sigmoid lanes: v = rcp(1 + 2^(mu*h + mq*q + c0)),            mu=-u*log2e
//   z lane:        v = 1 - 2*rcp(1 + 2^(mu*h + mq*q + c0)),      mu=+2u*log2e
// Gate values broadcast to all 4 lanes via DPP quad_perm (VALU-rate).

template<int CTRL>
__device__ __forceinline__ float qperm(float v) {
    return __builtin_bit_cast(float,
        __builtin_amdgcn_mov_dpp(__builtin_bit_cast(int, v), CTRL, 0xF, 0xF, true));
}

#define PF 16   // prefetch depth; over-prefetches harmlessly into adjacent ws region

__global__ __launch_bounds__(256)
void scan_kernel(const __half* __restrict__ pre,   // [B*T][2048] fp16, col = j*4+g
                 const float* __restrict__ uf_, const float* __restrict__ bf_,
                 const float* __restrict__ ui_, const float* __restrict__ bi_,
                 const float* __restrict__ uo_, const float* __restrict__ bo_,
                 const float* __restrict__ uc_, const float* __restrict__ bc_,
                 float* __restrict__ out) {
    const int tid   = blockIdx.x * 256 + threadIdx.x;
    const int g     = tid & 3;
    const int chain = tid >> 2;        // [0, 16384)
    const int j     = chain & 511;
    const int b     = chain >> 9;

    const float* up = (g == 0) ? uf_ : (g == 1) ? ui_ : (g == 2) ? uo_ : uc_;
    const float* bp = (g == 0) ? bf_ : (g == 1) ? bi_ : (g == 2) ? bo_ : bc_;
    const float u  = up[j];
    const float bb = bp[j];

    const float L2E = 1.44269504f;
    const bool  isz = (g == 3);
    const float mq  = isz ?  2.0f * L2E : -L2E;   // multiplies q (pre value)
    const float mu  = u * mq;                      // multiplies h
    const float c0  = bb * mq;                     // folded bias
    const float Av  = isz ? -2.0f : 1.0f;
    const float Bv  = isz ?  1.0f : 0.0f;
    const float K2  = 2.0f * L2E;                  // tanh(c) exponent scale

    const __half* p = pre + ((size_t)b * T_) * N_ + (size_t)j * 4 + g;
    float* o = out + ((size_t)b * T_) * H_ + j;

    float h = 0.0f, c = 0.0f;

    __half ring[PF];
#pragma unroll
    for (int i = 0; i < PF; i++)
        ring[i] = p[(size_t)i * N_];
    const __half* pl = p + (size_t)PF * N_;

#pragma unroll 16
    for (int t = 0; t < T_; ++t) {
        float qf = (float)ring[t & (PF - 1)];
        ring[t & (PF - 1)] = *pl;                 // over-prefetch past end: lands in ws, unused
        pl += (size_t)N_;

        float a    = __builtin_fmaf(qf, mq, c0);          // off h-chain
        float e    = __builtin_amdgcn_exp2f(__builtin_fmaf(h, mu, a));
        float s    = __builtin_amdgcn_rcpf(1.0f + e);
        float v    = __builtin_fmaf(Av, s, Bv);           // f/i/o sigmoid or z tanh

        float f  = qperm<0x00>(v);    // quad_perm [0,0,0,0]
        float ii = qperm<0x55>(v);    // [1,1,1,1]
        float oo = qperm<0xAA>(v);    // [2,2,2,2]
        float z  = qperm<0xFF>(v);    // [3,3,3,3]

        c = __builtin_fmaf(f, c, ii * z);

        float e2 = __builtin_amdgcn_exp2f(c * K2);
        float tc = __builtin_fmaf(-2.0f, __builtin_amdgcn_rcpf(1.0f + e2), 1.0f);
        h = oo * tc;

        if (g == 0)
            o[(size_t)t * H_] = h;
    }
}

// ---------------- launch ----------------

extern "C" void kernel_launch(void* const* d_in, const int* in_sizes, int n_in,
                              void* d_out, int out_size, void* d_ws, size_t ws_size,
                              hipStream_t stream) {
    const float* x  = (const float*)d_in[0];
    const float* Wf = (const float*)d_in[1];
    const float* uf = (const float*)d_in[2];
    const float* bf = (const float*)d_in[3];
    const float* Wi = (const float*)d_in[4];
    const float* ui = (const float*)d_in[5];
    const float* bi = (const float*)d_in[6];
    const float* Wo = (const float*)d_in[7];
    const float* uo = (const float*)d_in[8];
    const float* bo = (const float*)d_in[9];
    const float* Wc = (const float*)d_in[10];
    const float* uc = (const float*)d_in[11];
    const float* bc = (const float*)d_in[12];
    float* out = (float*)d_out;

    // ws layout: pre fp16 (256 MiB) | xh (64) | xl (64) | Wh (2) | Wl (2)  = 388 MiB
    const size_t preB = (size_t)B_ * T_ * N_ * 2;
    const size_t xB   = (size_t)B_ * T_ * K_ * 2;
    const size_t wB   = (size_t)N_ * K_ * 2;

    __half* pre = (__half*)d_ws;
    __bf16* xh  = (__bf16*)((char*)d_ws + preB);
    __bf16* xl  = (__bf16*)((char*)d_ws + preB + xB);
    __bf16* Wh  = (__bf16*)((char*)d_ws + preB + 2 * xB);
    __bf16* Wl  = (__bf16*)((char*)d_ws + preB + 2 * xB + wB);
    (void)ws_size; (void)wB;

    convert_x<<<(B_ * T_ * K_ / 4 + 255) / 256, 256, 0, stream>>>(x, xh, xl, B_ * T_ * K_ / 4);
    convert_w<<<(N_ * K_) / 256, 256, 0, stream>>>(Wf, Wi, Wo, Wc, Wh, Wl);

    // h_t, c_t outputs are zeros
    hipMemsetAsync((char*)d_out + (size_t)B_ * T_ * H_ * 4, 0,
                   2 * (size_t)B_ * H_ * 4, stream);

    const int M = B_ * T_;                                   // 65536
    gemm_bt<<<dim3((M / BM) * (N_ / BN)), 256, 0, stream>>>(xh, xl, Wh, Wl, pre);

    scan_kernel<<<dim3(B_ * H_ * 4 / 256), 256, 0, stream>>>(
        pre, uf, bf, ui, bi, uo, bo, uc, bc, out);
}